// Round 1
// baseline (4297.499 us; speedup 1.0000x reference)
//
#include <hip/hip_runtime.h>
#include <hip/hip_bf16.h>

constexpr int D = 128;

__global__ void fill_zero4(float4* __restrict__ p, long n4) {
  long i = (long)blockIdx.x * blockDim.x + threadIdx.x;
  long stride = (long)gridDim.x * blockDim.x;
  float4 z = make_float4(0.f, 0.f, 0.f, 0.f);
  for (; i < n4; i += stride) p[i] = z;
}

__global__ void transpose_w(const float* __restrict__ W, float* __restrict__ WT, int O, int K) {
  int i = blockIdx.x * blockDim.x + threadIdx.x;
  if (i < O * K) {
    int o = i / K, k = i - o * K;
    WT[k * O + o] = W[i];
  }
}

// 32 threads per edge; each lane moves one float4 of the source row into agg[dst] via atomics.
__global__ void scatter_edges(const float* __restrict__ h, const int* __restrict__ src,
                              const int* __restrict__ dst, float* __restrict__ agg,
                              float* __restrict__ deg, int E) {
  int t = blockIdx.x * blockDim.x + threadIdx.x;
  int e = t >> 5;
  if (e >= E) return;
  int lane = t & 31;
  int s = src[e], d = dst[e];
  float4 v = ((const float4*)(h + (size_t)s * D))[lane];
  float* a = agg + (size_t)d * D + lane * 4;
  atomicAdd(a + 0, v.x);
  atomicAdd(a + 1, v.y);
  atomicAdd(a + 2, v.z);
  atomicAdd(a + 3, v.w);
  if (lane == 0) atomicAdd(deg + d, 1.0f);
}

// out[r][c] = relu( mean[r] . WlT[:,c] + h[r] . WrT[:,c] + bl[c] )
// mean/h rows staged in LDS (broadcast reads); WT rows read coalesced (L1/L2-resident).
// NOTE: h and out may alias (in-place, row-wise) -> no __restrict__ on them.
template <int OC, bool RELU>
__global__ void sage_linear(const float* h, const float* __restrict__ agg,
                            const float* __restrict__ deg, const float* __restrict__ WlT,
                            const float* __restrict__ WrT, const float* __restrict__ bl,
                            float* out, int N) {
  constexpr int ROWS = 16;
  __shared__ float sm[ROWS][2 * D];
  int row0 = blockIdx.x * ROWS;
  int tid = threadIdx.x;
  for (int idx = tid; idx < ROWS * (D / 4); idx += blockDim.x) {
    int r = idx >> 5;  // D/4 = 32 float4 per row
    int q = idx & 31;
    int grow = row0 + r;
    if (grow < N) {
      float inv = 1.0f / fmaxf(deg[grow], 1.0f);
      float4 a = ((const float4*)(agg + (size_t)grow * D))[q];
      float4 hv = ((const float4*)(h + (size_t)grow * D))[q];
      float4 m = make_float4(a.x * inv, a.y * inv, a.z * inv, a.w * inv);
      ((float4*)&sm[r][0])[q] = m;
      ((float4*)&sm[r][D])[q] = hv;
    }
  }
  __syncthreads();
  int c = tid % OC;
  for (int r = tid / OC; r < ROWS; r += blockDim.x / OC) {
    int grow = row0 + r;
    if (grow >= N) break;
    float acc = bl[c];
#pragma unroll 8
    for (int k = 0; k < D; ++k) {
      acc = fmaf(sm[r][k], WlT[k * OC + c], acc);
      acc = fmaf(sm[r][D + k], WrT[k * OC + c], acc);
    }
    if (RELU) acc = fmaxf(acc, 0.0f);
    out[(size_t)grow * OC + c] = acc;
  }
}

extern "C" void kernel_launch(void* const* d_in, const int* in_sizes, int n_in,
                              void* d_out, int out_size, void* d_ws, size_t ws_size,
                              hipStream_t stream) {
  const float* x = (const float*)d_in[0];
  const int* ei = (const int*)d_in[1];
  const float* Wl0 = (const float*)d_in[2];
  const float* bl0 = (const float*)d_in[3];
  const float* Wr0 = (const float*)d_in[4];
  const float* Wl1 = (const float*)d_in[5];
  const float* bl1 = (const float*)d_in[6];
  const float* Wr1 = (const float*)d_in[7];
  const float* Wl2 = (const float*)d_in[8];
  const float* bl2 = (const float*)d_in[9];
  const float* Wr2 = (const float*)d_in[10];
  float* out = (float*)d_out;

  const int N = in_sizes[0] / D;  // 100000
  const int E = in_sizes[1] / 6;  // 625000

  float* ws_f = (float*)d_ws;
  float* agg = ws_f;                               // N*D
  float* h = ws_f + (size_t)N * D;                 // N*D
  float* deg = ws_f + (size_t)2 * N * D;           // N
  float* wt = deg + N;
  float* WlT0 = wt;
  float* WrT0 = WlT0 + D * D;
  float* WlT1 = WrT0 + D * D;
  float* WrT1 = WlT1 + D * D;
  float* WlT2 = WrT1 + D * D;  // 128x64
  float* WrT2 = WlT2 + D * 64;

  transpose_w<<<(D * D + 255) / 256, 256, 0, stream>>>(Wl0, WlT0, D, D);
  transpose_w<<<(D * D + 255) / 256, 256, 0, stream>>>(Wr0, WrT0, D, D);
  transpose_w<<<(D * D + 255) / 256, 256, 0, stream>>>(Wl1, WlT1, D, D);
  transpose_w<<<(D * D + 255) / 256, 256, 0, stream>>>(Wr1, WrT1, D, D);
  transpose_w<<<(64 * D + 255) / 256, 256, 0, stream>>>(Wl2, WlT2, 64, D);
  transpose_w<<<(64 * D + 255) / 256, 256, 0, stream>>>(Wr2, WrT2, 64, D);

  const int* src0 = ei;
  const int* dst0 = ei + E;
  const int* src1 = ei + 2 * E;
  const int* dst1 = ei + 3 * E;
  const int* src2 = ei + 4 * E;
  const int* dst2 = ei + 5 * E;

  long aggN4 = (long)N * D / 4;
  long degN4 = N / 4;
  int zg = 2048;
  int zgd = (int)((degN4 + 255) / 256);
  int sg = (int)(((long)E * 32 + 255) / 256);
  int lg = (N + 15) / 16;

  // layer 0
  fill_zero4<<<zg, 256, 0, stream>>>((float4*)agg, aggN4);
  fill_zero4<<<zgd, 256, 0, stream>>>((float4*)deg, degN4);
  scatter_edges<<<sg, 256, 0, stream>>>(x, src0, dst0, agg, deg, E);
  sage_linear<128, true><<<lg, 256, 0, stream>>>(x, agg, deg, WlT0, WrT0, bl0, h, N);

  // layer 1
  fill_zero4<<<zg, 256, 0, stream>>>((float4*)agg, aggN4);
  fill_zero4<<<zgd, 256, 0, stream>>>((float4*)deg, degN4);
  scatter_edges<<<sg, 256, 0, stream>>>(h, src1, dst1, agg, deg, E);
  sage_linear<128, true><<<lg, 256, 0, stream>>>(h, agg, deg, WlT1, WrT1, bl1, h, N);

  // layer 2
  fill_zero4<<<zg, 256, 0, stream>>>((float4*)agg, aggN4);
  fill_zero4<<<zgd, 256, 0, stream>>>((float4*)deg, degN4);
  scatter_edges<<<sg, 256, 0, stream>>>(h, src2, dst2, agg, deg, E);
  sage_linear<64, false><<<lg, 256, 0, stream>>>(h, agg, deg, WlT2, WrT2, bl2, out, N);
}

// Round 2
// 797.656 us; speedup vs baseline: 5.3877x; 5.3877x over previous
//
#include <hip/hip_runtime.h>
#include <hip/hip_bf16.h>

constexpr int D = 128;

__global__ void fill_int_zero(int* __restrict__ p, int n) {
  int i = blockIdx.x * blockDim.x + threadIdx.x;
  if (i < n) p[i] = 0;
}

// Combined transposed weight: WT[k][c], k in [0,256): k<128 -> Wl[c][k], else Wr[c][k-128]
__global__ void transpose_comb(const float* __restrict__ Wl, const float* __restrict__ Wr,
                               float* __restrict__ WT, int OC) {
  int t = blockIdx.x * blockDim.x + threadIdx.x;
  if (t < 256 * OC) {
    int k = t / OC, c = t - k * OC;
    WT[t] = (k < 128) ? Wl[c * 128 + k] : Wr[c * 128 + (k - 128)];
  }
}

__global__ void count_dst(const int* __restrict__ dst, int* __restrict__ cnt, int E) {
  int e = blockIdx.x * blockDim.x + threadIdx.x;
  if (e < E) atomicAdd(&cnt[dst[e]], 1);
}

// exclusive scan of cnt -> row_excl (per 256-block), block totals -> bsums
__global__ void scan_block(const int* __restrict__ cnt, int* __restrict__ row_excl,
                           int* __restrict__ bsums, int N) {
  __shared__ int sm[256];
  int i = blockIdx.x * 256 + threadIdx.x;
  int v = (i < N) ? cnt[i] : 0;
  sm[threadIdx.x] = v;
  __syncthreads();
  for (int off = 1; off < 256; off <<= 1) {
    int t = (threadIdx.x >= off) ? sm[threadIdx.x - off] : 0;
    __syncthreads();
    sm[threadIdx.x] += t;
    __syncthreads();
  }
  if (i < N) row_excl[i] = sm[threadIdx.x] - v;
  if (threadIdx.x == 255) bsums[blockIdx.x] = sm[255];
}

// exclusive scan of bsums in place (single block, nb <= 512)
__global__ void scan_sums(int* __restrict__ bsums, int nb) {
  __shared__ int sm[512];
  int v = (threadIdx.x < nb) ? bsums[threadIdx.x] : 0;
  sm[threadIdx.x] = v;
  __syncthreads();
  for (int off = 1; off < 512; off <<= 1) {
    int t = (threadIdx.x >= off) ? sm[threadIdx.x - off] : 0;
    __syncthreads();
    sm[threadIdx.x] += t;
    __syncthreads();
  }
  if (threadIdx.x < nb) bsums[threadIdx.x] = sm[threadIdx.x] - v;
}

__global__ void scan_finalize(int* __restrict__ row_start, const int* __restrict__ bsums,
                              int* __restrict__ cursor, int N) {
  int i = blockIdx.x * 256 + threadIdx.x;
  if (i < N) {
    int v = row_start[i] + bsums[blockIdx.x];
    row_start[i] = v;
    cursor[i] = v;
  }
}

__global__ void fill_edges(const int* __restrict__ src, const int* __restrict__ dst,
                           int* __restrict__ cursor, int* __restrict__ esrc, int E) {
  int e = blockIdx.x * blockDim.x + threadIdx.x;
  if (e < E) {
    int pos = atomicAdd(&cursor[dst[e]], 1);
    esrc[pos] = src[e];
  }
}

// One 64-lane wave per node: gather-sum neighbor rows, write mean. float2 per lane = 512B/row.
__global__ void aggregate_mean(const float* __restrict__ h, const int* __restrict__ esrc,
                               const int* __restrict__ row_start, const int* __restrict__ cnt,
                               float* __restrict__ mean, int N) {
  int node = blockIdx.x * (blockDim.x >> 6) + (threadIdx.x >> 6);
  if (node >= N) return;
  int lane = threadIdx.x & 63;
  int start = row_start[node];
  int deg = cnt[node];
  const float2* hp = (const float2*)h;  // row stride 64 float2
  float2 a0 = make_float2(0.f, 0.f), a1 = make_float2(0.f, 0.f);
  int j = 0;
  for (; j + 1 < deg; j += 2) {
    int s0 = esrc[start + j];
    int s1 = esrc[start + j + 1];
    float2 v0 = hp[(size_t)s0 * 64 + lane];
    float2 v1 = hp[(size_t)s1 * 64 + lane];
    a0.x += v0.x; a0.y += v0.y;
    a1.x += v1.x; a1.y += v1.y;
  }
  if (j < deg) {
    int s0 = esrc[start + j];
    float2 v0 = hp[(size_t)s0 * 64 + lane];
    a0.x += v0.x; a0.y += v0.y;
  }
  float inv = 1.0f / fmaxf((float)deg, 1.0f);
  ((float2*)mean)[(size_t)node * 64 + lane] = make_float2((a0.x + a1.x) * inv, (a0.y + a1.y) * inv);
}

// out[r][c] = (RELU?) mean[r,:].Wl[c,:] + h[r,:].Wr[c,:] + bl[c]
// Combined K=256: sm row = [mean(128) | h(128)], WT[k][c] combined.
// h/out may alias row-wise (in-place) -> no __restrict__ on them.
template <int OC, bool RELU>
__global__ void sage_linear(const float* h, const float* __restrict__ mean,
                            const float* __restrict__ WT, const float* __restrict__ bl,
                            float* out, int N) {
  constexpr int ROWS = 16;
  constexpr int GROUPS = 256 / OC;
  constexpr int RPT = ROWS / GROUPS;  // rows per thread
  __shared__ float sm[ROWS][2 * D];
  int row0 = blockIdx.x * ROWS;
  int tid = threadIdx.x;
  // stage: 16 rows x 64 float4 (mean -> k[0,128), h -> k[128,256))
  for (int idx = tid; idx < ROWS * 64; idx += 256) {
    int r = idx >> 6;
    int q = idx & 63;
    int grow = row0 + r;
    if (grow < N) {
      float4 v;
      if (q < 32)
        v = ((const float4*)(mean + (size_t)grow * D))[q];
      else
        v = ((const float4*)(h + (size_t)grow * D))[q - 32];
      ((float4*)&sm[r][0])[q] = v;
    }
  }
  __syncthreads();
  int c = tid % OC;
  int g = tid / OC;
  const float* wcol = WT + c;
  float acc[RPT];
#pragma unroll
  for (int r = 0; r < RPT; ++r) acc[r] = bl[c];
#pragma unroll 4
  for (int k = 0; k < 2 * D; k += 4) {
    float w0 = wcol[(k + 0) * OC];
    float w1 = wcol[(k + 1) * OC];
    float w2 = wcol[(k + 2) * OC];
    float w3 = wcol[(k + 3) * OC];
#pragma unroll
    for (int r = 0; r < RPT; ++r) {
      float4 s = ((const float4*)&sm[g * RPT + r][0])[k >> 2];
      acc[r] = fmaf(s.x, w0, acc[r]);
      acc[r] = fmaf(s.y, w1, acc[r]);
      acc[r] = fmaf(s.z, w2, acc[r]);
      acc[r] = fmaf(s.w, w3, acc[r]);
    }
  }
#pragma unroll
  for (int r = 0; r < RPT; ++r) {
    int grow = row0 + g * RPT + r;
    if (grow < N) {
      float v = acc[r];
      if (RELU) v = fmaxf(v, 0.0f);
      out[(size_t)grow * OC + c] = v;
    }
  }
}

extern "C" void kernel_launch(void* const* d_in, const int* in_sizes, int n_in,
                              void* d_out, int out_size, void* d_ws, size_t ws_size,
                              hipStream_t stream) {
  const float* x = (const float*)d_in[0];
  const int* ei = (const int*)d_in[1];
  const float* Wl0 = (const float*)d_in[2];
  const float* bl0 = (const float*)d_in[3];
  const float* Wr0 = (const float*)d_in[4];
  const float* Wl1 = (const float*)d_in[5];
  const float* bl1 = (const float*)d_in[6];
  const float* Wr1 = (const float*)d_in[7];
  const float* Wl2 = (const float*)d_in[8];
  const float* bl2 = (const float*)d_in[9];
  const float* Wr2 = (const float*)d_in[10];
  float* out = (float*)d_out;

  const int N = in_sizes[0] / D;  // 100000
  const int E = in_sizes[1] / 6;  // 625000

  float* ws_f = (float*)d_ws;
  float* mean = ws_f;                     // N*D
  float* h = ws_f + (size_t)N * D;        // N*D
  float* WT0 = ws_f + (size_t)2 * N * D;  // 256*128
  float* WT1 = WT0 + 256 * 128;
  float* WT2 = WT1 + 256 * 128;  // 256*64
  int* cnt = (int*)(WT2 + 256 * 64);
  int* row_start = cnt + N;
  int* cursor = row_start + N;
  int* bsums = cursor + N;
  int* esrc = bsums + 512;

  const int nbN = (N + 255) / 256;   // scan blocks
  const int nbE = (E + 255) / 256;

  transpose_comb<<<(256 * 128 + 255) / 256, 256, 0, stream>>>(Wl0, Wr0, WT0, 128);
  transpose_comb<<<(256 * 128 + 255) / 256, 256, 0, stream>>>(Wl1, Wr1, WT1, 128);
  transpose_comb<<<(256 * 64 + 255) / 256, 256, 0, stream>>>(Wl2, Wr2, WT2, 64);

  int aggGrid = (N * 64 + 255) / 256;   // one wave per node, 4 waves/block
  int linGrid = (N + 15) / 16;

  for (int layer = 0; layer < 3; ++layer) {
    const int* srcL = ei + (size_t)(2 * layer) * E;
    const int* dstL = srcL + E;
    const float* hin = (layer == 0) ? x : h;

    fill_int_zero<<<nbN, 256, 0, stream>>>(cnt, N);
    count_dst<<<nbE, 256, 0, stream>>>(dstL, cnt, E);
    scan_block<<<nbN, 256, 0, stream>>>(cnt, row_start, bsums, N);
    scan_sums<<<1, 512, 0, stream>>>(bsums, nbN);
    scan_finalize<<<nbN, 256, 0, stream>>>(row_start, bsums, cursor, N);
    fill_edges<<<nbE, 256, 0, stream>>>(srcL, dstL, cursor, esrc, E);
    aggregate_mean<<<aggGrid, 256, 0, stream>>>(hin, esrc, row_start, cnt, mean, N);

    if (layer == 0)
      sage_linear<128, true><<<linGrid, 256, 0, stream>>>(x, mean, WT0, bl0, h, N);
    else if (layer == 1)
      sage_linear<128, true><<<linGrid, 256, 0, stream>>>(h, mean, WT1, bl1, h, N);
    else
      sage_linear<64, false><<<linGrid, 256, 0, stream>>>(h, mean, WT2, bl2, out, N);
  }
}

// Round 3
// 490.616 us; speedup vs baseline: 8.7594x; 1.6258x over previous
//
#include <hip/hip_runtime.h>
#include <hip/hip_bf16.h>

constexpr int D = 128;

using bf16x8 = __attribute__((ext_vector_type(8))) short;
using f32x4 = __attribute__((ext_vector_type(4))) float;

__device__ inline ushort f2bf(float f) {
  union { float f; uint u; } v; v.f = f;
  uint r = v.u + 0x7fff + ((v.u >> 16) & 1);
  return (ushort)(r >> 16);
}
__device__ inline float bflo(uint p) {
  union { uint u; float f; } v; v.u = p << 16; return v.f;
}
__device__ inline float bfhi(uint p) {
  union { uint u; float f; } v; v.u = p & 0xffff0000u; return v.f;
}

__global__ void fill_int_zero(int* __restrict__ p, int n) {
  int i = blockIdx.x * blockDim.x + threadIdx.x;
  if (i < n) p[i] = 0;
}

// x fp32 -> bf16 (packed ushort), vectorized
__global__ void cvt_f32_bf16(const float4* __restrict__ x, uint2* __restrict__ o, long n4) {
  long i = (long)blockIdx.x * blockDim.x + threadIdx.x;
  long stride = (long)gridDim.x * blockDim.x;
  for (; i < n4; i += stride) {
    float4 v = x[i];
    uint2 r;
    r.x = (uint)f2bf(v.x) | ((uint)f2bf(v.y) << 16);
    r.y = (uint)f2bf(v.z) | ((uint)f2bf(v.w) << 16);
    o[i] = r;
  }
}

// Combined weight, bf16, row-major [OC][256]: k<128 -> Wl[c][k], else Wr[c][k-128]
__global__ void prep_w(const float* __restrict__ Wl, const float* __restrict__ Wr,
                       ushort* __restrict__ Wc, int OC) {
  int t = blockIdx.x * blockDim.x + threadIdx.x;
  if (t < OC * 256) {
    int c = t >> 8, k = t & 255;
    float v = (k < 128) ? Wl[c * 128 + k] : Wr[c * 128 + (k - 128)];
    Wc[t] = f2bf(v);
  }
}

__global__ void count_dst(const int* __restrict__ dst, int* __restrict__ cnt, int E) {
  int e = blockIdx.x * blockDim.x + threadIdx.x;
  if (e < E) atomicAdd(&cnt[dst[e]], 1);
}

__global__ void scan_block(const int* __restrict__ cnt, int* __restrict__ row_excl,
                           int* __restrict__ bsums, int N) {
  __shared__ int sm[256];
  int i = blockIdx.x * 256 + threadIdx.x;
  int v = (i < N) ? cnt[i] : 0;
  sm[threadIdx.x] = v;
  __syncthreads();
  for (int off = 1; off < 256; off <<= 1) {
    int t = (threadIdx.x >= off) ? sm[threadIdx.x - off] : 0;
    __syncthreads();
    sm[threadIdx.x] += t;
    __syncthreads();
  }
  if (i < N) row_excl[i] = sm[threadIdx.x] - v;
  if (threadIdx.x == 255) bsums[blockIdx.x] = sm[255];
}

__global__ void scan_sums(int* __restrict__ bsums, int nb) {
  __shared__ int sm[512];
  int v = (threadIdx.x < nb) ? bsums[threadIdx.x] : 0;
  sm[threadIdx.x] = v;
  __syncthreads();
  for (int off = 1; off < 512; off <<= 1) {
    int t = (threadIdx.x >= off) ? sm[threadIdx.x - off] : 0;
    __syncthreads();
    sm[threadIdx.x] += t;
    __syncthreads();
  }
  if (threadIdx.x < nb) bsums[threadIdx.x] = sm[threadIdx.x] - v;
}

__global__ void scan_finalize(int* __restrict__ row_start, const int* __restrict__ bsums,
                              int* __restrict__ cursor, int N) {
  int i = blockIdx.x * 256 + threadIdx.x;
  if (i < N) {
    int v = row_start[i] + bsums[blockIdx.x];
    row_start[i] = v;
    cursor[i] = v;
  }
}

__global__ void fill_edges(const int* __restrict__ src, const int* __restrict__ dst,
                           int* __restrict__ cursor, int* __restrict__ esrc, int E) {
  int e = blockIdx.x * blockDim.x + threadIdx.x;
  if (e < E) {
    int pos = atomicAdd(&cursor[dst[e]], 1);
    esrc[pos] = src[e];
  }
}

// One 64-lane wave per node: gather-sum bf16 neighbor rows (fp32 acc), write bf16 mean.
// Each lane owns 2 channels (one packed uint per row).
__global__ void aggregate_mean(const ushort* __restrict__ h, const int* __restrict__ esrc,
                               const int* __restrict__ row_start, const int* __restrict__ cnt,
                               ushort* __restrict__ mean, int N) {
  int node = blockIdx.x * (blockDim.x >> 6) + (threadIdx.x >> 6);
  if (node >= N) return;
  int lane = threadIdx.x & 63;
  int start = row_start[node];
  int deg = cnt[node];
  const uint* hp = (const uint*)h;  // row stride 64 uints
  float ax = 0.f, ay = 0.f, bx = 0.f, by = 0.f;
  int j = 0;
  for (; j + 1 < deg; j += 2) {
    uint v0 = hp[(size_t)esrc[start + j] * 64 + lane];
    uint v1 = hp[(size_t)esrc[start + j + 1] * 64 + lane];
    ax += bflo(v0); ay += bfhi(v0);
    bx += bflo(v1); by += bfhi(v1);
  }
  if (j < deg) {
    uint v0 = hp[(size_t)esrc[start + j] * 64 + lane];
    ax += bflo(v0); ay += bfhi(v0);
  }
  float inv = 1.0f / fmaxf((float)deg, 1.0f);
  uint r = (uint)f2bf((ax + bx) * inv) | ((uint)f2bf((ay + by) * inv) << 16);
  ((uint*)mean)[(size_t)node * 64 + lane] = r;
}

// MFMA linear: C[N x OC] = [mean|h] (N x 256, bf16) @ Wc^T + bl, optional relu.
// Block: 64 rows x OC cols, 4 waves; wave w owns cols [w*OC/4, +OC/4) (CT 16-col tiles),
// B-frags held in registers (Wc row-major => contiguous 16B frag loads).
template <int OC, bool RELU, bool F32OUT>
__global__ void sage_linear_mfma(const ushort* __restrict__ mb, const ushort* __restrict__ hb,
                                 const ushort* __restrict__ Wc, const float* __restrict__ bl,
                                 void* __restrict__ outv, int N) {
  constexpr int CT = OC / 64;  // col-tiles per wave: 128 -> 2, 64 -> 1
  int tid = threadIdx.x;
  int w = tid >> 6, lane = tid & 63;
  int g = lane >> 4, r16 = lane & 15;
  int r0 = blockIdx.x * 64;
  int c0 = w * (OC / 4);

  bf16x8 b[CT][8];
  float bias[CT];
#pragma unroll
  for (int ct = 0; ct < CT; ++ct) {
    int col = c0 + ct * 16 + r16;
    const ushort* wrow = Wc + (size_t)col * 256 + g * 8;
#pragma unroll
    for (int ks = 0; ks < 8; ++ks)
      b[ct][ks] = *reinterpret_cast<const bf16x8*>(wrow + ks * 32);
    bias[ct] = bl[col];
  }

  f32x4 acc[4][CT];
#pragma unroll
  for (int rt = 0; rt < 4; ++rt)
#pragma unroll
    for (int ct = 0; ct < CT; ++ct)
      acc[rt][ct] = (f32x4){0.f, 0.f, 0.f, 0.f};

#pragma unroll
  for (int rt = 0; rt < 4; ++rt) {
    int row = r0 + rt * 16 + r16;
    row = min(row, N - 1);
    const ushort* am = mb + (size_t)row * 128 + g * 8;
    const ushort* ah = hb + (size_t)row * 128 + g * 8;
#pragma unroll
    for (int ks = 0; ks < 4; ++ks) {
      bf16x8 a = *reinterpret_cast<const bf16x8*>(am + ks * 32);
#pragma unroll
      for (int ct = 0; ct < CT; ++ct)
        acc[rt][ct] = __builtin_amdgcn_mfma_f32_16x16x32_bf16(a, b[ct][ks], acc[rt][ct], 0, 0, 0);
    }
#pragma unroll
    for (int ks = 0; ks < 4; ++ks) {
      bf16x8 a = *reinterpret_cast<const bf16x8*>(ah + ks * 32);
#pragma unroll
      for (int ct = 0; ct < CT; ++ct)
        acc[rt][ct] = __builtin_amdgcn_mfma_f32_16x16x32_bf16(a, b[ct][ks + 4], acc[rt][ct], 0, 0, 0);
    }
  }

  // C/D layout: col = lane&15, row = (lane>>4)*4 + reg  [m89-verified]
#pragma unroll
  for (int rt = 0; rt < 4; ++rt) {
#pragma unroll
    for (int ct = 0; ct < CT; ++ct) {
      int col = c0 + ct * 16 + r16;
#pragma unroll
      for (int reg = 0; reg < 4; ++reg) {
        int row = r0 + rt * 16 + g * 4 + reg;
        if (row < N) {
          float v = acc[rt][ct][reg] + bias[ct];
          if (RELU) v = fmaxf(v, 0.0f);
          if (F32OUT)
            ((float*)outv)[(size_t)row * OC + col] = v;
          else
            ((ushort*)outv)[(size_t)row * OC + col] = f2bf(v);
        }
      }
    }
  }
}

extern "C" void kernel_launch(void* const* d_in, const int* in_sizes, int n_in,
                              void* d_out, int out_size, void* d_ws, size_t ws_size,
                              hipStream_t stream) {
  const float* x = (const float*)d_in[0];
  const int* ei = (const int*)d_in[1];
  const float* Wl0 = (const float*)d_in[2];
  const float* bl0 = (const float*)d_in[3];
  const float* Wr0 = (const float*)d_in[4];
  const float* Wl1 = (const float*)d_in[5];
  const float* bl1 = (const float*)d_in[6];
  const float* Wr1 = (const float*)d_in[7];
  const float* Wl2 = (const float*)d_in[8];
  const float* bl2 = (const float*)d_in[9];
  const float* Wr2 = (const float*)d_in[10];
  float* out = (float*)d_out;

  const int N = in_sizes[0] / D;  // 100000
  const int E = in_sizes[1] / 6;  // 625000

  char* ws = (char*)d_ws;
  size_t featB = (size_t)N * D * sizeof(ushort);  // 25.6 MB
  ushort* hb0 = (ushort*)ws;
  ushort* hb1 = (ushort*)(ws + featB);
  ushort* mb = (ushort*)(ws + 2 * featB);
  ushort* Wc0 = (ushort*)(ws + 3 * featB);
  ushort* Wc1 = Wc0 + 128 * 256;
  ushort* Wc2 = Wc1 + 128 * 256;
  int* cnt = (int*)(Wc2 + 64 * 256);
  int* row_start = cnt + N;
  int* cursor = row_start + N;
  int* bsums = cursor + N;
  int* esrc = bsums + 512;

  const int nbN = (N + 255) / 256;
  const int nbE = (E + 255) / 256;
  const int aggGrid = (N * 64 + 255) / 256;
  const int linGrid = (N + 63) / 64;

  cvt_f32_bf16<<<2048, 256, 0, stream>>>((const float4*)x, (uint2*)hb0, (long)N * D / 4);
  prep_w<<<(128 * 256 + 255) / 256, 256, 0, stream>>>(Wl0, Wr0, Wc0, 128);
  prep_w<<<(128 * 256 + 255) / 256, 256, 0, stream>>>(Wl1, Wr1, Wc1, 128);
  prep_w<<<(64 * 256 + 255) / 256, 256, 0, stream>>>(Wl2, Wr2, Wc2, 64);

  for (int layer = 0; layer < 3; ++layer) {
    const int* srcL = ei + (size_t)(2 * layer) * E;
    const int* dstL = srcL + E;
    const ushort* hin = (layer == 1) ? hb1 : hb0;

    fill_int_zero<<<nbN, 256, 0, stream>>>(cnt, N);
    count_dst<<<nbE, 256, 0, stream>>>(dstL, cnt, E);
    scan_block<<<nbN, 256, 0, stream>>>(cnt, row_start, bsums, N);
    scan_sums<<<1, 512, 0, stream>>>(bsums, nbN);
    scan_finalize<<<nbN, 256, 0, stream>>>(row_start, bsums, cursor, N);
    fill_edges<<<nbE, 256, 0, stream>>>(srcL, dstL, cursor, esrc, E);
    aggregate_mean<<<aggGrid, 256, 0, stream>>>(hin, esrc, row_start, cnt, mb, N);

    if (layer == 0)
      sage_linear_mfma<128, true, false><<<linGrid, 256, 0, stream>>>(mb, hb0, Wc0, bl0, hb1, N);
    else if (layer == 1)
      sage_linear_mfma<128, true, false><<<linGrid, 256, 0, stream>>>(mb, hb1, Wc1, bl1, hb0, N);
    else
      sage_linear_mfma<64, false, true><<<linGrid, 256, 0, stream>>>(mb, hb0, Wc2, bl2, out, N);
  }
}